// Round 5
// baseline (96.492 us; speedup 1.0000x reference)
//
#include <hip/hip_runtime.h>
#include <hip/hip_bf16.h>

// Poincare pairwise distance, c=1:
//   d(x,p) = acosh(1 + 2*||x-p||^2 / ((1-||x||^2)(1-||p||^2)))
// B=16384, N=4096, D=64. Output 16384x4096 f32 (256 MiB) -> write-bound.
//
// Round 5: persistent pipelined blocks. Grid = 1024 = exactly 4 blocks/CU
// (one generation, zero churn). Each block: 128 emb rows x 512-proto band,
// processed as 8 proto tiles of 64 with double-buffered LDS. Proto tile t+1
// is loaded to registers BEFORE computing tile t (issue-early/write-late),
// so HBM load latency hides under MFMA+epilogue and stores issue
// continuously instead of in per-block bursts.

constexpr int BATCH = 16384;
constexpr int NCON  = 4096;
constexpr int DIM   = 64;
constexpr int TM    = 128;          // emb rows per block
constexpr int TN    = 64;           // protos per tile
constexpr int NTILE = 8;            // tiles per block (512-proto band)
constexpr int BAND  = TN * NTILE;   // 512
constexpr float LN2 = 0.6931471805599453f;

typedef float  f32x4  __attribute__((ext_vector_type(4)));
typedef __bf16 bf16x8 __attribute__((ext_vector_type(8)));

__global__ __launch_bounds__(256, 4)
void poincare_pairwise_kernel(const float* __restrict__ emb,
                              const float* __restrict__ proto,
                              float* __restrict__ out)
{
    // XOR-swizzle k ^= (row&7)<<3 for conflict-free ds_read_b128.
    __shared__ __bf16 As[TM * DIM];       // 16 KiB (emb, staged once)
    __shared__ __bf16 Bs[2][TN * DIM];    // 16 KiB (proto, double-buffered)
    __shared__ float  x2s[TM];
    __shared__ float  p2s[2][TN];
    __shared__ float  rps[2][TN];

    const int tid  = threadIdx.x;
    const int bid  = blockIdx.x;
    const int m0   = (bid >> 3) * TM;     // 128 mt values
    const int n0   = (bid & 7) * BAND;    // 8 bands of 512

    const int lane = tid & 63;
    const int wid  = tid >> 6;
    const int lr   = lane & 15;
    const int g    = lane >> 4;
    const int lk   = g * 8;

    // ---------- stage emb tile (128 x 64), once ----------
    #pragma unroll
    for (int p = 0; p < 8; ++p) {
        int flat = p * 256 + tid;
        int row  = flat >> 4, kq = flat & 15;
        f32x4 v = *reinterpret_cast<const f32x4*>(emb + (size_t)(m0 + row) * DIM + kq * 4);
        float ss = v.x*v.x + v.y*v.y + v.z*v.z + v.w*v.w;
        ss += __shfl_xor(ss, 1);
        ss += __shfl_xor(ss, 2);
        ss += __shfl_xor(ss, 4);
        ss += __shfl_xor(ss, 8);
        if (kq == 0) x2s[row] = ss;
        __bf16 b4[4] = {(__bf16)v.x, (__bf16)v.y, (__bf16)v.z, (__bf16)v.w};
        int ke = (kq * 4) ^ ((row & 7) << 3);
        *reinterpret_cast<uint2*>(&As[row * DIM + ke]) = *reinterpret_cast<const uint2*>(b4);
    }
    // ---------- stage proto tile 0 (64 x 64) ----------
    #pragma unroll
    for (int p = 0; p < 4; ++p) {
        int flat = p * 256 + tid;
        int row  = flat >> 4, kq = flat & 15;
        f32x4 v = *reinterpret_cast<const f32x4*>(proto + (size_t)(n0 + row) * DIM + kq * 4);
        float ss = v.x*v.x + v.y*v.y + v.z*v.z + v.w*v.w;
        ss += __shfl_xor(ss, 1);
        ss += __shfl_xor(ss, 2);
        ss += __shfl_xor(ss, 4);
        ss += __shfl_xor(ss, 8);
        if (kq == 0) { p2s[0][row] = ss; rps[0][row] = __builtin_amdgcn_rcpf(1.0f - ss); }
        __bf16 b4[4] = {(__bf16)v.x, (__bf16)v.y, (__bf16)v.z, (__bf16)v.w};
        int ke = (kq * 4) ^ ((row & 7) << 3);
        *reinterpret_cast<uint2*>(&Bs[0][row * DIM + ke]) = *reinterpret_cast<const uint2*>(b4);
    }
    __syncthreads();

    // ---------- per-block persistent state ----------
    // Wave owns 32 emb rows (2 row-frags: wid*16+lr and 64+wid*16+lr) x 64 protos.
    bf16x8 xfrag[2][2];                   // [kk][rf]
    float  x2[2], crow[2];
    float* rowp[2];
    #pragma unroll
    for (int rf = 0; rf < 2; ++rf) {
        int xrow = rf * 64 + wid * 16 + lr;
        #pragma unroll
        for (int kk = 0; kk < 2; ++kk) {
            int ke = (kk * 32 + lk) ^ ((xrow & 7) << 3);
            xfrag[kk][rf] = *reinterpret_cast<const bf16x8*>(&As[xrow * DIM + ke]);
        }
        x2[rf]   = x2s[xrow];
        crow[rf] = 2.0f * __builtin_amdgcn_rcpf(1.0f - x2[rf]);
        rowp[rf] = out + (size_t)(m0 + xrow) * NCON + n0;
    }

    int cur = 0;
    #pragma unroll 2
    for (int t = 0; t < NTILE; ++t) {
        // ---- prefetch next proto tile to regs (issued before compute) ----
        f32x4 pv[4];
        if (t < NTILE - 1) {
            const float* pbase = proto + (size_t)(n0 + (t + 1) * TN) * DIM;
            #pragma unroll
            for (int p = 0; p < 4; ++p) {
                int flat = p * 256 + tid;
                pv[p] = *reinterpret_cast<const f32x4*>(pbase + (flat >> 4) * DIM + (flat & 15) * 4);
            }
        }

        // ---- MFMA: 2 row-frags x 4 proto-frags x 2 k-steps ----
        f32x4 acc[2][4] = {};             // [rf][pf]
        #pragma unroll
        for (int kk = 0; kk < 2; ++kk) {
            bf16x8 pfrag[4];
            #pragma unroll
            for (int pf = 0; pf < 4; ++pf) {
                int prow = pf * 16 + lr;
                int kep  = (kk * 32 + lk) ^ ((prow & 7) << 3);
                pfrag[pf] = *reinterpret_cast<const bf16x8*>(&Bs[cur][prow * DIM + kep]);
            }
            #pragma unroll
            for (int pf = 0; pf < 4; ++pf) {
                acc[0][pf] = __builtin_amdgcn_mfma_f32_16x16x32_bf16(pfrag[pf], xfrag[kk][0], acc[0][pf], 0, 0, 0);
                acc[1][pf] = __builtin_amdgcn_mfma_f32_16x16x32_bf16(pfrag[pf], xfrag[kk][1], acc[1][pf], 0, 0, 0);
            }
        }

        // ---- epilogue: distance + store (64B full lines per 4-lane group) ----
        #pragma unroll
        for (int pf = 0; pf < 4; ++pf) {
            int   col = pf * 16 + g * 4;
            f32x4 p2  = *reinterpret_cast<const f32x4*>(&p2s[cur][col]);
            f32x4 rp  = *reinterpret_cast<const f32x4*>(&rps[cur][col]);
            #pragma unroll
            for (int rf = 0; rf < 2; ++rf) {
                f32x4 dv;
                #pragma unroll
                for (int j = 0; j < 4; ++j) {
                    float xpp = x2[rf] + p2[j];
                    float crp = crow[rf] * rp[j];
                    float sq  = fmaxf(xpp - 2.0f * acc[rf][pf][j], 0.0f);
                    float tt  = sq * crp;
                    float s   = __builtin_amdgcn_sqrtf(tt * (tt + 2.0f));
                    dv[j]     = LN2 * __builtin_amdgcn_logf(1.0f + tt + s);
                }
                *reinterpret_cast<f32x4*>(rowp[rf] + t * TN + col) = dv;
            }
        }

        // ---- write prefetched tile to the other LDS buffer ----
        if (t < NTILE - 1) {
            #pragma unroll
            for (int p = 0; p < 4; ++p) {
                int flat = p * 256 + tid;
                int row  = flat >> 4, kq = flat & 15;
                f32x4 v  = pv[p];
                float ss = v.x*v.x + v.y*v.y + v.z*v.z + v.w*v.w;
                ss += __shfl_xor(ss, 1);
                ss += __shfl_xor(ss, 2);
                ss += __shfl_xor(ss, 4);
                ss += __shfl_xor(ss, 8);
                if (kq == 0) { p2s[cur ^ 1][row] = ss; rps[cur ^ 1][row] = __builtin_amdgcn_rcpf(1.0f - ss); }
                __bf16 b4[4] = {(__bf16)v.x, (__bf16)v.y, (__bf16)v.z, (__bf16)v.w};
                int ke = (kq * 4) ^ ((row & 7) << 3);
                *reinterpret_cast<uint2*>(&Bs[cur ^ 1][row * DIM + ke]) = *reinterpret_cast<const uint2*>(b4);
            }
            __syncthreads();
            cur ^= 1;
        }
    }
}

extern "C" void kernel_launch(void* const* d_in, const int* in_sizes, int n_in,
                              void* d_out, int out_size, void* d_ws, size_t ws_size,
                              hipStream_t stream) {
    const float* emb   = (const float*)d_in[0];
    const float* proto = (const float*)d_in[1];
    float* out = (float*)d_out;

    dim3 grid((BATCH / TM) * (NCON / BAND));  // 128 * 8 = 1024 = 4 blocks/CU
    dim3 block(256);
    poincare_pairwise_kernel<<<grid, block, 0, stream>>>(emb, proto, out);
}

// Round 6
// 65.505 us; speedup vs baseline: 1.4731x; 1.4731x over previous
//
#include <hip/hip_runtime.h>
#include <hip/hip_bf16.h>

// Poincare pairwise distance, c=1:
//   d(x,p) = acosh(1 + 2*||x-p||^2 / ((1-||x||^2)(1-||p||^2)))
// B=16384, N=4096, D=64. Output 16384x4096 f32 (256 MiB) -> write-bound.
//
// Round 6: two-phase. A cheap pre-pass writes to ws:
//   - bf16 copies of emb/proto laid out EXACTLY as the main kernel's
//     XOR-swizzled LDS tiles (k ^= (row&7)<<3), so hot-kernel staging is a
//     pure linear uint4 copy (no cvt/shfl/rcp in the 8192-block kernel);
//   - per-row x2, crow = 2/(1-x2); per-proto p2, rp = 1/(1-p2).
// Main kernel keeps R4's structure (best so far): 64 emb x 128 proto tile,
// one barrier, barrier-free epilogue, dwordx4 stores. LDS 24 KB -> 6
// blocks/CU for better store/VALU overlap.

constexpr int BATCH = 16384;
constexpr int NCON  = 4096;
constexpr int DIM   = 64;
constexpr int TM    = 64;           // emb rows per block
constexpr int TN    = 128;          // protos per block
constexpr float LN2 = 0.6931471805599453f;

// ws layout (bytes), all 16B-aligned:
constexpr size_t WS_EMB   = 0;                          // 256 tiles x 8 KiB = 2 MiB
constexpr size_t WS_PROTO = (size_t)2 << 20;            // 32 tiles x 16 KiB = 512 KiB
constexpr size_t WS_X2    = WS_PROTO + (512u << 10);    // f32[16384]
constexpr size_t WS_CROW  = WS_X2   + 64u * 1024;       // f32[16384]
constexpr size_t WS_P2    = WS_CROW + 64u * 1024;       // f32[4096]
constexpr size_t WS_RP    = WS_P2   + 16u * 1024;       // f32[4096]

typedef float  f32x4  __attribute__((ext_vector_type(4)));
typedef __bf16 bf16x8 __attribute__((ext_vector_type(8)));

// ---------------- pre-pass ----------------
// gid sections: [0,131072) emb-tile chunks (16B each),
//               [131072,163840) proto-tile chunks,
//               [163840,180224) emb row norms,
//               [180224,184320) proto row norms.
__global__ __launch_bounds__(256)
void prepass_kernel(const float* __restrict__ emb,
                    const float* __restrict__ proto,
                    char* __restrict__ ws)
{
    int gid = blockIdx.x * 256 + threadIdx.x;
    if (gid < 131072) {
        // emb bf16 swizzled tiles: tile mt (64x64), chunk = 8 bf16 elements.
        int c = gid;
        int mt = c >> 9, within = c & 511;
        int e0  = within * 8;
        int row = e0 >> 6;
        int k0  = (e0 & 63) ^ ((row & 7) << 3);   // 8-aligned; low 3 bits pass through
        const float* src = emb + (size_t)(mt * 64 + row) * DIM + k0;
        f32x4 a = *reinterpret_cast<const f32x4*>(src);
        f32x4 b = *reinterpret_cast<const f32x4*>(src + 4);
        bf16x8 v;
        v[0]=(__bf16)a.x; v[1]=(__bf16)a.y; v[2]=(__bf16)a.z; v[3]=(__bf16)a.w;
        v[4]=(__bf16)b.x; v[5]=(__bf16)b.y; v[6]=(__bf16)b.z; v[7]=(__bf16)b.w;
        *reinterpret_cast<bf16x8*>(ws + WS_EMB + (size_t)c * 16) = v;
    } else if (gid < 163840) {
        // proto bf16 swizzled tiles: tile nt (128x64).
        int c = gid - 131072;
        int nt = c >> 10, within = c & 1023;
        int e0  = within * 8;
        int row = e0 >> 6;
        int k0  = (e0 & 63) ^ ((row & 7) << 3);
        const float* src = proto + (size_t)(nt * 128 + row) * DIM + k0;
        f32x4 a = *reinterpret_cast<const f32x4*>(src);
        f32x4 b = *reinterpret_cast<const f32x4*>(src + 4);
        bf16x8 v;
        v[0]=(__bf16)a.x; v[1]=(__bf16)a.y; v[2]=(__bf16)a.z; v[3]=(__bf16)a.w;
        v[4]=(__bf16)b.x; v[5]=(__bf16)b.y; v[6]=(__bf16)b.z; v[7]=(__bf16)b.w;
        *reinterpret_cast<bf16x8*>(ws + WS_PROTO + (size_t)c * 16) = v;
    } else if (gid < 180224) {
        // emb norms
        int r = gid - 163840;
        const f32x4* src = reinterpret_cast<const f32x4*>(emb + (size_t)r * DIM);
        float s = 0.0f;
        #pragma unroll
        for (int i = 0; i < 16; ++i) {
            f32x4 v = src[i];
            s += v.x*v.x + v.y*v.y + v.z*v.z + v.w*v.w;
        }
        reinterpret_cast<float*>(ws + WS_X2)[r]   = s;
        reinterpret_cast<float*>(ws + WS_CROW)[r] = 2.0f * __builtin_amdgcn_rcpf(1.0f - s);
    } else if (gid < 184320) {
        // proto norms
        int r = gid - 180224;
        const f32x4* src = reinterpret_cast<const f32x4*>(proto + (size_t)r * DIM);
        float s = 0.0f;
        #pragma unroll
        for (int i = 0; i < 16; ++i) {
            f32x4 v = src[i];
            s += v.x*v.x + v.y*v.y + v.z*v.z + v.w*v.w;
        }
        reinterpret_cast<float*>(ws + WS_P2)[r] = s;
        reinterpret_cast<float*>(ws + WS_RP)[r] = __builtin_amdgcn_rcpf(1.0f - s);
    }
}

// ---------------- main kernel ----------------
__global__ __launch_bounds__(256, 4)
void poincare_pairwise_kernel(const char* __restrict__ ws,
                              float* __restrict__ out)
{
    __shared__ __bf16 As[TM * DIM];   // 8 KiB  (emb tile, pre-swizzled)
    __shared__ __bf16 Bs[TN * DIM];   // 16 KiB (proto tile, pre-swizzled)

    const int tid = threadIdx.x;
    const int bid = blockIdx.x;
    const int mt  = bid >> 5;          // 256 tiles along M
    const int nt  = bid & 31;          // 32 tiles along N
    const int m0  = mt * TM;
    const int n0  = nt * TN;

    // ---------- staging: pure linear uint4 copy of pre-swizzled tiles ----------
    {
        const uint4* esrc = reinterpret_cast<const uint4*>(ws + WS_EMB + (size_t)mt * 8192);
        uint4* edst = reinterpret_cast<uint4*>(As);
        edst[tid]       = esrc[tid];
        edst[256 + tid] = esrc[256 + tid];
        const uint4* psrc = reinterpret_cast<const uint4*>(ws + WS_PROTO + (size_t)nt * 16384);
        uint4* pdst = reinterpret_cast<uint4*>(Bs);
        #pragma unroll
        for (int i = 0; i < 4; ++i)
            pdst[i * 256 + tid] = psrc[i * 256 + tid];
    }

    const int lane = tid & 63;
    const int wid  = tid >> 6;         // wave -> 16-row emb strip
    const int lr   = lane & 15;
    const int g    = lane >> 4;
    const int lk   = g * 8;
    const int xrow = wid * 16 + lr;

    // per-lane row params (issued while staging is in flight)
    const float x2   = reinterpret_cast<const float*>(ws + WS_X2)[m0 + xrow];
    const float crow = reinterpret_cast<const float*>(ws + WS_CROW)[m0 + xrow];
    float* rowp = out + (size_t)(m0 + xrow) * NCON + n0;

    __syncthreads();   // the ONLY barrier

    // ---------- MFMA: wave owns 16 emb rows x 128 protos ----------
    bf16x8 xfrag[2];
    #pragma unroll
    for (int kk = 0; kk < 2; ++kk) {
        int ke = (kk * 32 + lk) ^ ((xrow & 7) << 3);
        xfrag[kk] = *reinterpret_cast<const bf16x8*>(&As[xrow * DIM + ke]);
    }
    f32x4 acc[8] = {};
    #pragma unroll
    for (int kk = 0; kk < 2; ++kk) {
        bf16x8 pfrag[8];
        #pragma unroll
        for (int pf = 0; pf < 8; ++pf) {
            int prow = pf * 16 + lr;
            int kep  = (kk * 32 + lk) ^ ((prow & 7) << 3);
            pfrag[pf] = *reinterpret_cast<const bf16x8*>(&Bs[prow * DIM + kep]);
        }
        #pragma unroll
        for (int pf = 0; pf < 8; ++pf)
            acc[pf] = __builtin_amdgcn_mfma_f32_16x16x32_bf16(
                pfrag[pf], xfrag[kk], acc[pf], 0, 0, 0);
    }

    // ---------- epilogue: distance + store (no barriers) ----------
    // D layout: col = lane&15 -> emb row (lr); row = g*4+j -> proto idx.
    const float* p2a = reinterpret_cast<const float*>(ws + WS_P2) + n0;
    const float* rpa = reinterpret_cast<const float*>(ws + WS_RP) + n0;
    #pragma unroll
    for (int pf = 0; pf < 8; ++pf) {
        int   col = pf * 16 + g * 4;
        f32x4 p2  = *reinterpret_cast<const f32x4*>(p2a + col);
        f32x4 rp  = *reinterpret_cast<const f32x4*>(rpa + col);
        f32x4 dv;
        #pragma unroll
        for (int j = 0; j < 4; ++j) {
            float sq = fmaxf(x2 + p2[j] - 2.0f * acc[pf][j], 0.0f);
            float tt = sq * (crow * rp[j]);
            float s  = __builtin_amdgcn_sqrtf(tt * (tt + 2.0f));
            dv[j]    = LN2 * __builtin_amdgcn_logf(1.0f + tt + s);
        }
        *reinterpret_cast<f32x4*>(rowp + col) = dv;
    }
}

extern "C" void kernel_launch(void* const* d_in, const int* in_sizes, int n_in,
                              void* d_out, int out_size, void* d_ws, size_t ws_size,
                              hipStream_t stream) {
    const float* emb   = (const float*)d_in[0];
    const float* proto = (const float*)d_in[1];
    float* out = (float*)d_out;
    char* ws   = (char*)d_ws;

    prepass_kernel<<<720, 256, 0, stream>>>(emb, proto, ws);          // 184320 threads
    dim3 grid((BATCH / TM) * (NCON / TN));                            // 256 * 32 = 8192
    poincare_pairwise_kernel<<<grid, 256, 0, stream>>>(ws, out);
}